// Round 1
// baseline (1042.217 us; speedup 1.0000x reference)
//
#include <hip/hip_runtime.h>
#include <hip/hip_bf16.h>

// RFAConv fused: per-pixel v[k]=attn*relu(bn1(dwconv)) (K=1152), then out = relu(bn2(W2 @ v + cb))
// W2 = conv_w [256][1152] since space-to-depth + stride-3 conv == 1x1 conv over C*9 channels.

#define CCH  128
#define OCN  256
#define HH   96
#define WWD  96
#define KCH  1152   // 128*9
#define NPOS 16     // pixels per block
#define VP   1160   // vlds pitch in bf16 (pad: word-stride 580 ≡ 4 mod 32 -> 2-way, free)
#define WP   42     // w2t pitch in bf16 (word-stride 21, odd -> conflict-free-ish reads)

__global__ __launch_bounds__(256) void rfa_fused_kernel(
    const float* __restrict__ x,      // [8,128,96,96]
    const float* __restrict__ w1,     // [128,9]
    const float* __restrict__ gfw,    // [1152,9]
    const float* __restrict__ bn1g, const float* __restrict__ bn1b,
    const float* __restrict__ bn1m, const float* __restrict__ bn1v,
    const float* __restrict__ W2,     // [256,1152]
    const float* __restrict__ cbias,  // [256]
    const float* __restrict__ bn2g, const float* __restrict__ bn2b,
    const float* __restrict__ bn2m, const float* __restrict__ bn2v,
    float* __restrict__ out)          // [8,256,96,96]
{
    __shared__ __hip_bfloat16 vlds[NPOS][VP];
    __shared__ __hip_bfloat16 w2t[OCN][WP];

    const int tid  = threadIdx.x;
    const int blk  = blockIdx.x;
    const int tile = blk % 576;           // 9216/16 tiles per image, 6 per row
    const int b    = blk / 576;
    const int h    = tile / 6;
    const int w0   = (tile % 6) * NPOS;

    // ---------------- phase 1: v[pos][k] -> LDS (bf16) ----------------
    {
        const int wo = tid & 15;          // pixel in tile
        const int cq = tid >> 4;          // 0..15
        const int w  = w0 + wo;
        const float* xb = x + (size_t)b * CCH * HH * WWD;
        #pragma unroll 1
        for (int it = 0; it < CCH / 16; ++it) {
            const int c = it * 16 + cq;
            const float* xc = xb + (size_t)c * (HH * WWD);
            float nb[9];
            #pragma unroll
            for (int dy = 0; dy < 3; ++dy) {
                const int hy = h + dy - 1;
                const bool hok = (unsigned)hy < (unsigned)HH;
                #pragma unroll
                for (int dx = 0; dx < 3; ++dx) {
                    const int wx = w + dx - 1;
                    const bool ok = hok && ((unsigned)wx < (unsigned)WWD);
                    nb[dy*3+dx] = ok ? xc[hy*WWD + wx] : 0.f;
                }
            }
            float pooled = 0.f;
            #pragma unroll
            for (int t = 0; t < 9; ++t) pooled += nb[t];
            pooled *= (1.f/9.f);
            // softmax over n of pooled*w1[c][n]
            float at[9];
            float mx = -1e30f;
            #pragma unroll
            for (int n = 0; n < 9; ++n) { at[n] = pooled * w1[c*9+n]; mx = fmaxf(mx, at[n]); }
            float ssum = 0.f;
            #pragma unroll
            for (int n = 0; n < 9; ++n) { at[n] = __expf(at[n] - mx); ssum += at[n]; }
            const float rs = 1.f / ssum;
            #pragma unroll
            for (int n = 0; n < 9; ++n) {
                const int ch = c*9 + n;
                const float* gw = gfw + ch*9;
                float f = 0.f;
                #pragma unroll
                for (int t = 0; t < 9; ++t) f = fmaf(nb[t], gw[t], f);
                const float sc = bn1g[ch] * rsqrtf(bn1v[ch] + 1e-5f);
                f = (f - bn1m[ch]) * sc + bn1b[ch];
                f = fmaxf(f, 0.f) * (at[n] * rs);
                vlds[wo][ch] = __float2bfloat16(f);
            }
        }
    }
    __syncthreads();

    // ---------------- phase 2: out[oc][pos] = W2 @ v ----------------
    const int ocg = tid & 63;             // oc = ocg + 64*j
    const int pg  = tid >> 6;             // wave id -> 4 pixels (uniform per wave)
    const int p0  = pg * 4;
    float acc[4][4] = {{0.f}};            // [j][pp]

    for (int kt = 0; kt < KCH / 32; ++kt) {
        if (kt) __syncthreads();
        // stage W2[:, kt*32 .. +32] as bf16, coalesced
        #pragma unroll
        for (int i = 0; i < 32; ++i) {    // 8192 elems / 256 thr
            const int e  = i * 256 + tid;
            const int oc = e >> 5;
            const int kl = e & 31;
            w2t[oc][kl] = __float2bfloat16(W2[(size_t)oc * KCH + kt*32 + kl]);
        }
        __syncthreads();
        const int kb = kt * 32;
        #pragma unroll 1
        for (int kl = 0; kl < 32; kl += 4) {
            float wv[4][4];
            #pragma unroll
            for (int j = 0; j < 4; ++j) {
                const __hip_bfloat162* pw =
                    reinterpret_cast<const __hip_bfloat162*>(&w2t[ocg + 64*j][kl]);
                float2 w01 = __bfloat1622float2(pw[0]);
                float2 w23 = __bfloat1622float2(pw[1]);
                wv[j][0]=w01.x; wv[j][1]=w01.y; wv[j][2]=w23.x; wv[j][3]=w23.y;
            }
            #pragma unroll
            for (int pp = 0; pp < 4; ++pp) {
                const __hip_bfloat162* pv =
                    reinterpret_cast<const __hip_bfloat162*>(&vlds[p0+pp][kb+kl]);
                float2 v01 = __bfloat1622float2(pv[0]);   // wave-uniform addr: LDS broadcast
                float2 v23 = __bfloat1622float2(pv[1]);
                const float vv0=v01.x, vv1=v01.y, vv2=v23.x, vv3=v23.y;
                #pragma unroll
                for (int j = 0; j < 4; ++j) {
                    acc[j][pp] = fmaf(wv[j][0], vv0, acc[j][pp]);
                    acc[j][pp] = fmaf(wv[j][1], vv1, acc[j][pp]);
                    acc[j][pp] = fmaf(wv[j][2], vv2, acc[j][pp]);
                    acc[j][pp] = fmaf(wv[j][3], vv3, acc[j][pp]);
                }
            }
        }
    }

    // epilogue: bn2 + relu, out[b][oc][h][w0+p0+pp]
    #pragma unroll
    for (int j = 0; j < 4; ++j) {
        const int oc = ocg + 64*j;
        const float s2 = bn2g[oc] * rsqrtf(bn2v[oc] + 1e-5f);
        const float t2 = (cbias[oc] - bn2m[oc]) * s2 + bn2b[oc];
        float* op = out + (((size_t)b * OCN + oc) * HH + h) * WWD + w0 + p0;
        #pragma unroll
        for (int pp = 0; pp < 4; ++pp) {
            op[pp] = fmaxf(fmaf(acc[j][pp], s2, t2), 0.f);
        }
    }
}

extern "C" void kernel_launch(void* const* d_in, const int* in_sizes, int n_in,
                              void* d_out, int out_size, void* d_ws, size_t ws_size,
                              hipStream_t stream) {
    const float* xx   = (const float*)d_in[0];
    const float* w1   = (const float*)d_in[1];
    const float* gfw  = (const float*)d_in[2];
    const float* bn1g = (const float*)d_in[3];
    const float* bn1b = (const float*)d_in[4];
    const float* bn1m = (const float*)d_in[5];
    const float* bn1v = (const float*)d_in[6];
    const float* W2   = (const float*)d_in[7];
    const float* cb   = (const float*)d_in[8];
    const float* bn2g = (const float*)d_in[9];
    const float* bn2b = (const float*)d_in[10];
    const float* bn2m = (const float*)d_in[11];
    const float* bn2v = (const float*)d_in[12];
    float* o = (float*)d_out;

    dim3 grid(8 * 576);
    dim3 blockd(256);
    rfa_fused_kernel<<<grid, blockd, 0, stream>>>(
        xx, w1, gfw, bn1g, bn1b, bn1m, bn1v, W2, cb, bn2g, bn2b, bn2m, bn2v, o);
}

// Round 3
// 283.759 us; speedup vs baseline: 3.6729x; 3.6729x over previous
//
#include <hip/hip_runtime.h>
#include <hip/hip_bf16.h>

// RFAConv fused, MFMA version.
// v[pix][k] = attn*relu(bn1(dwconv))  (K = C*9 = 1152), computed per k-chunk into LDS.
// out[oc][pix] = relu(bn2(W2 @ v^T + cb)) via mfma_f32_16x16x32_bf16.
// GEMM roles: A = W2 (oc x K), B = v^T (K x pix) -> C[oc][pix] stores coalesce over pix.

#define CCH  128
#define OCN  256
#define HH   96
#define WWD  96
#define KCH  1152
#define PIMG 9216     // 96*96
#define BNP  128      // pixels per block
#define NBLK 72       // pixel-blocks per image (9216/128)
#define CC   32       // channels per k-chunk
#define KC   288      // k per chunk (CC*9)
#define VP   296      // LDS pitch (bf16): mult of 8 (16B-aligned b128), word-stride 148 -> 2-way only
#define NT   512

using short8 = __attribute__((ext_vector_type(8))) short;
using f32x4  = __attribute__((ext_vector_type(4))) float;
using float4v = __attribute__((ext_vector_type(4))) float;

__device__ __forceinline__ ushort bf16bits(float f) {
    __hip_bfloat16 h = __float2bfloat16(f);
    return *reinterpret_cast<ushort*>(&h);
}

__global__ void w2cvt_kernel(const float* __restrict__ W2, ushort* __restrict__ W2bf) {
    int i = blockIdx.x * NT + threadIdx.x;
    if (i < OCN * KCH) W2bf[i] = bf16bits(W2[i]);
}

template<bool WSBF>
__global__ __launch_bounds__(NT, 4) void rfa_mfma_kernel(
    const float* __restrict__ x,      // [8,128,96,96]
    const float* __restrict__ w1,     // [128,9]
    const float* __restrict__ gfw,    // [1152,9]
    const float* __restrict__ bn1g, const float* __restrict__ bn1b,
    const float* __restrict__ bn1m, const float* __restrict__ bn1v,
    const float* __restrict__ W2f,    // fp32 [256][1152]
    const ushort* __restrict__ W2bf,  // bf16 [256][1152] (valid iff WSBF)
    const float* __restrict__ cbias,
    const float* __restrict__ bn2g, const float* __restrict__ bn2b,
    const float* __restrict__ bn2m, const float* __restrict__ bn2v,
    float* __restrict__ out)          // [8,256,96,96]
{
    __shared__ ushort vlds[BNP * VP];   // 75776 B

    const int tid = threadIdx.x;
    const int b   = blockIdx.x / NBLK;
    const int P0  = (blockIdx.x % NBLK) * BNP;

    // ---- phase-1 mapping: 128 pixels x 4 channel-subgroups ----
    const int px   = tid & (BNP - 1);
    const int p    = P0 + px;
    const int h    = p / WWD;
    const int w    = p - h * WWD;
    const int cgrp = __builtin_amdgcn_readfirstlane(tid >> 7);  // 0..3, wave-uniform

    // ---- GEMM mapping: 8 waves = 4 (oc) x 2 (pix) ----
    const int lane = tid & 63;
    const int wid  = tid >> 6;
    const int wm   = wid >> 1;     // oc group of 64
    const int wn   = wid & 1;      // pixel group of 64
    const int l15  = lane & 15;
    const int lhi  = lane >> 4;

    f32x4 acc[4][4] = {};          // [mi][ni]

    const float* xb = x + (size_t)b * CCH * PIMG;
    // hoisted A base index: (oc_row_base)*KCH + k-lane offset
    const int abase = (wm * 64 + l15) * KCH + lhi * 8;

    for (int ck = 0; ck < 4; ++ck) {
        __syncthreads();   // vlds free (prev chunk's GEMM done)

        // ---------- phase 1: v for channels [ck*32, ck*32+32) ----------
        #pragma unroll 1
        for (int pass = 0; pass < 8; ++pass) {
            const int cl = pass * 4 + cgrp;       // 0..31, wave-uniform
            const int c  = ck * CC + cl;
            const float* xc = xb + (size_t)c * PIMG;

            float nb[9];
            #pragma unroll
            for (int dy = 0; dy < 3; ++dy) {
                const int hy = h + dy - 1;
                const bool hok = (unsigned)hy < (unsigned)HH;
                const float* xr = xc + hy * WWD;
                #pragma unroll
                for (int dx = 0; dx < 3; ++dx) {
                    const int wx = w + dx - 1;
                    const bool ok = hok && ((unsigned)wx < (unsigned)WWD);
                    nb[dy * 3 + dx] = ok ? xr[wx] : 0.f;
                }
            }
            float pooled = 0.f;
            #pragma unroll
            for (int t = 0; t < 9; ++t) pooled += nb[t];
            pooled *= (1.f / 9.f);

            const float* w1c = w1 + c * 9;        // wave-uniform -> s_load
            float at[9];
            float mx = -1e30f;
            #pragma unroll
            for (int n = 0; n < 9; ++n) { at[n] = pooled * w1c[n]; mx = fmaxf(mx, at[n]); }
            float ss = 0.f;
            #pragma unroll
            for (int n = 0; n < 9; ++n) { at[n] = __expf(at[n] - mx); ss += at[n]; }
            const float rs = 1.f / ss;

            const int ch0 = c * 9;
            ushort* vp = vlds + px * VP + cl * 9;
            #pragma unroll
            for (int n = 0; n < 9; ++n) {
                const int ch = ch0 + n;
                const float* gw = gfw + ch * 9;   // wave-uniform
                float f = 0.f;
                #pragma unroll
                for (int t = 0; t < 9; ++t) f = fmaf(nb[t], gw[t], f);
                const float sc = bn1g[ch] * rsqrtf(bn1v[ch] + 1e-5f);
                f = (f - bn1m[ch]) * sc + bn1b[ch];
                f = fmaxf(f, 0.f) * (at[n] * rs);
                vp[n] = bf16bits(f);
            }
        }
        __syncthreads();   // vlds chunk ready

        // ---------- GEMM over this k-chunk: 9 ksteps of 32 ----------
        const int k0 = ck * KC;
        #pragma unroll 3
        for (int kk = 0; kk < 9; ++kk) {
            short8 afr[4], bfr[4];
            #pragma unroll
            for (int mi = 0; mi < 4; ++mi) {
                const int ai = abase + mi * 16 * KCH + k0 + kk * 32;
                if constexpr (WSBF) {
                    afr[mi] = *reinterpret_cast<const short8*>(W2bf + ai);
                } else {
                    const float4v f0 = *reinterpret_cast<const float4v*>(W2f + ai);
                    const float4v f1 = *reinterpret_cast<const float4v*>(W2f + ai + 4);
                    short8 a;
                    a[0] = (short)bf16bits(f0[0]); a[1] = (short)bf16bits(f0[1]);
                    a[2] = (short)bf16bits(f0[2]); a[3] = (short)bf16bits(f0[3]);
                    a[4] = (short)bf16bits(f1[0]); a[5] = (short)bf16bits(f1[1]);
                    a[6] = (short)bf16bits(f1[2]); a[7] = (short)bf16bits(f1[3]);
                    afr[mi] = a;
                }
            }
            #pragma unroll
            for (int ni = 0; ni < 4; ++ni) {
                const ushort* bp = vlds + (wn * 64 + ni * 16 + l15) * VP + kk * 32 + lhi * 8;
                bfr[ni] = *reinterpret_cast<const short8*>(bp);
            }
            #pragma unroll
            for (int mi = 0; mi < 4; ++mi)
                #pragma unroll
                for (int ni = 0; ni < 4; ++ni)
                    acc[mi][ni] = __builtin_amdgcn_mfma_f32_16x16x32_bf16(
                        afr[mi], bfr[ni], acc[mi][ni], 0, 0, 0);
        }
    }

    // ---------- epilogue: bn2 + relu, coalesced over pixels ----------
    const int P0w = P0 + wn * 64;
    #pragma unroll
    for (int mi = 0; mi < 4; ++mi) {
        #pragma unroll
        for (int r = 0; r < 4; ++r) {
            const int oc = wm * 64 + mi * 16 + lhi * 4 + r;
            const float s2 = bn2g[oc] * rsqrtf(bn2v[oc] + 1e-5f);
            const float t2 = (cbias[oc] - bn2m[oc]) * s2 + bn2b[oc];
            float* op = out + ((size_t)(b * OCN + oc)) * PIMG + P0w;
            #pragma unroll
            for (int ni = 0; ni < 4; ++ni)
                op[ni * 16 + l15] = fmaxf(fmaf(acc[mi][ni][r], s2, t2), 0.f);
        }
    }
}

extern "C" void kernel_launch(void* const* d_in, const int* in_sizes, int n_in,
                              void* d_out, int out_size, void* d_ws, size_t ws_size,
                              hipStream_t stream) {
    const float* xx   = (const float*)d_in[0];
    const float* w1   = (const float*)d_in[1];
    const float* gfw  = (const float*)d_in[2];
    const float* bn1g = (const float*)d_in[3];
    const float* bn1b = (const float*)d_in[4];
    const float* bn1m = (const float*)d_in[5];
    const float* bn1v = (const float*)d_in[6];
    const float* W2   = (const float*)d_in[7];
    const float* cb   = (const float*)d_in[8];
    const float* bn2g = (const float*)d_in[9];
    const float* bn2b = (const float*)d_in[10];
    const float* bn2m = (const float*)d_in[11];
    const float* bn2v = (const float*)d_in[12];
    float* o = (float*)d_out;

    const size_t w2bytes = (size_t)OCN * KCH * sizeof(ushort);
    dim3 grid(8 * NBLK);
    dim3 blk(NT);

    if (ws_size >= w2bytes) {
        ushort* W2bf = (ushort*)d_ws;
        w2cvt_kernel<<<(OCN * KCH + NT - 1) / NT, NT, 0, stream>>>(W2, W2bf);
        rfa_mfma_kernel<true><<<grid, blk, 0, stream>>>(
            xx, w1, gfw, bn1g, bn1b, bn1m, bn1v, W2, W2bf, cb,
            bn2g, bn2b, bn2m, bn2v, o);
    } else {
        rfa_mfma_kernel<false><<<grid, blk, 0, stream>>>(
            xx, w1, gfw, bn1g, bn1b, bn1m, bn1v, W2, nullptr, cb,
            bn2g, bn2b, bn2m, bn2v, o);
    }
}

// Round 4
// 245.569 us; speedup vs baseline: 4.2441x; 1.1555x over previous
//
#include <hip/hip_runtime.h>
#include <hip/hip_bf16.h>

// RFAConv fused, MFMA + double-buffered pipeline.
// v[pix][k] = attn*relu(dwconv_bn1folded)  (K = C*9 = 1152), per 288-k chunk into LDS (2 bufs).
// out[oc][pix] = relu(bn2(W2 @ v^T + cb)) via mfma_f32_16x16x32_bf16.
// One barrier per chunk: GEMM(ck) overlaps phase-1(ck+1) across waves.

#define CCH  128
#define OCN  256
#define HH   96
#define WWD  96
#define KCH  1152
#define PIMG 9216     // 96*96
#define BNP  64       // pixels per block
#define NBLK 144      // 9216/64
#define CC   32       // channels per chunk
#define KC   288      // k per chunk
#define VP   296      // LDS pitch (shorts): mult of 8, word-stride 148 (mod 32 = 20)
#define NT   512

using short8  = __attribute__((ext_vector_type(8))) short;
using f32x4   = __attribute__((ext_vector_type(4))) float;
using float4v = __attribute__((ext_vector_type(4))) float;

__device__ __forceinline__ ushort bf16bits(float f) {
    __hip_bfloat16 h = __float2bfloat16(f);
    return *reinterpret_cast<ushort*>(&h);
}

// ---- prepass: W2->bf16, fold bn1 into dwconv weights, pre-scale w1 by 1/9 ----
__global__ void prep_kernel(const float* __restrict__ W2, const float* __restrict__ gfw,
                            const float* __restrict__ bn1g, const float* __restrict__ bn1b,
                            const float* __restrict__ bn1m, const float* __restrict__ bn1v,
                            const float* __restrict__ w1,
                            ushort* __restrict__ W2bf, float* __restrict__ gws,
                            float* __restrict__ shiftv, float* __restrict__ w1s) {
    int i = blockIdx.x * 256 + threadIdx.x;
    if (i < OCN * KCH) {
        W2bf[i] = bf16bits(W2[i]);
    } else if (i < OCN * KCH + KCH) {
        const int ch = i - OCN * KCH;
        const float sc = bn1g[ch] * rsqrtf(bn1v[ch] + 1e-5f);
        shiftv[ch] = bn1b[ch] - bn1m[ch] * sc;
        #pragma unroll
        for (int t = 0; t < 9; ++t) gws[ch * 12 + t] = gfw[ch * 9 + t] * sc;
    } else if (i < OCN * KCH + KCH + CCH) {
        const int c = i - OCN * KCH - KCH;
        #pragma unroll
        for (int n = 0; n < 9; ++n) w1s[c * 12 + n] = w1[c * 9 + n] * (1.f / 9.f);
    }
}

template<bool FAST>
__global__ __launch_bounds__(NT, 4) void rfa_mfma2_kernel(
    const float* __restrict__ x,
    const float* __restrict__ w1,   const float* __restrict__ gfw,
    const float* __restrict__ bn1g, const float* __restrict__ bn1b,
    const float* __restrict__ bn1m, const float* __restrict__ bn1v,
    const float* __restrict__ W2f,
    const ushort* __restrict__ W2bf, const float* __restrict__ gws,
    const float* __restrict__ shiftv, const float* __restrict__ w1s,
    const float* __restrict__ cbias,
    const float* __restrict__ bn2g, const float* __restrict__ bn2b,
    const float* __restrict__ bn2m, const float* __restrict__ bn2v,
    float* __restrict__ out)
{
    __shared__ ushort vlds[2][BNP * VP];   // 2 x 37888 B = 75776 B -> 2 blocks/CU

    const int tid = threadIdx.x;
    const int b   = blockIdx.x / NBLK;
    const int P0  = (blockIdx.x % NBLK) * BNP;

    const int px  = tid & 63;              // lane == pixel
    const int p   = P0 + px;
    const int h   = p / WWD;
    const int w   = p - h * WWD;
    const int wid = tid >> 6;              // wave id 0..7 (uniform)
    const int l15 = px & 15;
    const int lhi = px >> 4;

    f32x4 acc[2][4] = {};                  // [mi][ni]

    const float* xb = x + (size_t)b * CCH * PIMG;
    const int abase = (wid * 32 + l15) * KCH + lhi * 8;

    for (int ck = 0; ck < 4; ++ck) {
        ushort* vbuf = vlds[ck & 1];

        // ---------- phase 1: 4 channels per wave ----------
        #pragma unroll 2
        for (int pass = 0; pass < 4; ++pass) {
            const int cl = wid * 4 + pass;        // 0..31 within chunk
            const int c  = ck * CC + cl;
            const float* xc = xb + (size_t)c * PIMG;

            float nb[9];
            #pragma unroll
            for (int dy = 0; dy < 3; ++dy) {
                const int hy = h + dy - 1;
                const bool hok = (unsigned)hy < (unsigned)HH;
                const float* xr = xc + hy * WWD;
                #pragma unroll
                for (int dx = 0; dx < 3; ++dx) {
                    const int wx = w + dx - 1;
                    const bool ok = hok && ((unsigned)wx < (unsigned)WWD);
                    nb[dy * 3 + dx] = ok ? xr[wx] : 0.f;
                }
            }
            float psum = 0.f;
            #pragma unroll
            for (int t = 0; t < 9; ++t) psum += nb[t];

            float at[9];
            float ss = 0.f;
            if constexpr (FAST) {
                const float* w1r = w1s + c * 12;  // pre-scaled by 1/9
                #pragma unroll
                for (int n = 0; n < 9; ++n) { at[n] = __expf(psum * w1r[n]); ss += at[n]; }
            } else {
                const float pooled = psum * (1.f / 9.f);
                const float* w1r = w1 + c * 9;
                #pragma unroll
                for (int n = 0; n < 9; ++n) { at[n] = __expf(pooled * w1r[n]); ss += at[n]; }
            }
            const float rs = 1.f / ss;

            const int ch0 = c * 9;
            ushort* vp = vbuf + px * VP + cl * 9;
            #pragma unroll
            for (int n = 0; n < 9; ++n) {
                const int ch = ch0 + n;
                float f;
                if constexpr (FAST) {
                    const float* gr = gws + ch * 12;
                    f = shiftv[ch];
                    #pragma unroll
                    for (int t = 0; t < 9; ++t) f = fmaf(nb[t], gr[t], f);
                } else {
                    const float* gr = gfw + ch * 9;
                    float cv = 0.f;
                    #pragma unroll
                    for (int t = 0; t < 9; ++t) cv = fmaf(nb[t], gr[t], cv);
                    const float sc = bn1g[ch] * rsqrtf(bn1v[ch] + 1e-5f);
                    f = (cv - bn1m[ch]) * sc + bn1b[ch];
                }
                f = fmaxf(f, 0.f) * (at[n] * rs);
                vp[n] = bf16bits(f);
            }
        }
        __syncthreads();   // vbuf(ck) ready; buf(ck-2) GEMM finished by all waves

        // ---------- GEMM chunk ck: 9 ksteps of 32 ----------
        const int k0 = ck * KC;
        #pragma unroll 3
        for (int kk = 0; kk < 9; ++kk) {
            short8 afr[2], bfr[4];
            #pragma unroll
            for (int mi = 0; mi < 2; ++mi) {
                const int ai = abase + mi * 16 * KCH + k0 + kk * 32;
                if constexpr (FAST) {
                    afr[mi] = *reinterpret_cast<const short8*>(W2bf + ai);
                } else {
                    const float4v f0 = *reinterpret_cast<const float4v*>(W2f + ai);
                    const float4v f1 = *reinterpret_cast<const float4v*>(W2f + ai + 4);
                    short8 a;
                    a[0] = (short)bf16bits(f0[0]); a[1] = (short)bf16bits(f0[1]);
                    a[2] = (short)bf16bits(f0[2]); a[3] = (short)bf16bits(f0[3]);
                    a[4] = (short)bf16bits(f1[0]); a[5] = (short)bf16bits(f1[1]);
                    a[6] = (short)bf16bits(f1[2]); a[7] = (short)bf16bits(f1[3]);
                    afr[mi] = a;
                }
            }
            #pragma unroll
            for (int ni = 0; ni < 4; ++ni) {
                const ushort* bp = vbuf + (ni * 16 + l15) * VP + kk * 32 + lhi * 8;
                bfr[ni] = *reinterpret_cast<const short8*>(bp);
            }
            #pragma unroll
            for (int mi = 0; mi < 2; ++mi)
                #pragma unroll
                for (int ni = 0; ni < 4; ++ni)
                    acc[mi][ni] = __builtin_amdgcn_mfma_f32_16x16x32_bf16(
                        afr[mi], bfr[ni], acc[mi][ni], 0, 0, 0);
        }
    }

    // ---------- epilogue: bn2 + relu ----------
    #pragma unroll
    for (int mi = 0; mi < 2; ++mi) {
        #pragma unroll
        for (int r = 0; r < 4; ++r) {
            const int oc = wid * 32 + mi * 16 + lhi * 4 + r;
            const float s2 = bn2g[oc] * rsqrtf(bn2v[oc] + 1e-5f);
            const float t2 = (cbias[oc] - bn2m[oc]) * s2 + bn2b[oc];
            float* op = out + ((size_t)(b * OCN + oc)) * PIMG + P0;
            #pragma unroll
            for (int ni = 0; ni < 4; ++ni)
                op[ni * 16 + l15] = fmaxf(fmaf(acc[mi][ni][r], s2, t2), 0.f);
        }
    }
}

extern "C" void kernel_launch(void* const* d_in, const int* in_sizes, int n_in,
                              void* d_out, int out_size, void* d_ws, size_t ws_size,
                              hipStream_t stream) {
    const float* xx   = (const float*)d_in[0];
    const float* w1   = (const float*)d_in[1];
    const float* gfw  = (const float*)d_in[2];
    const float* bn1g = (const float*)d_in[3];
    const float* bn1b = (const float*)d_in[4];
    const float* bn1m = (const float*)d_in[5];
    const float* bn1v = (const float*)d_in[6];
    const float* W2   = (const float*)d_in[7];
    const float* cb   = (const float*)d_in[8];
    const float* bn2g = (const float*)d_in[9];
    const float* bn2b = (const float*)d_in[10];
    const float* bn2m = (const float*)d_in[11];
    const float* bn2v = (const float*)d_in[12];
    float* o = (float*)d_out;

    // d_ws layout: W2bf ushort[294912] | gws f32[1152*12] | shift f32[1152] | w1s f32[128*12]
    const size_t off_gws   = (size_t)OCN * KCH * sizeof(ushort);          // 589824
    const size_t off_shift = off_gws + (size_t)KCH * 12 * sizeof(float);  // 645120
    const size_t off_w1s   = off_shift + (size_t)KCH * sizeof(float);     // 649728
    const size_t ws_need   = off_w1s + (size_t)CCH * 12 * sizeof(float);  // 655872

    dim3 grid(8 * NBLK);
    dim3 blk(NT);

    if (ws_size >= ws_need) {
        ushort* W2bf  = (ushort*)d_ws;
        float*  gws   = (float*)((char*)d_ws + off_gws);
        float*  shf   = (float*)((char*)d_ws + off_shift);
        float*  w1s   = (float*)((char*)d_ws + off_w1s);
        const int ptot = OCN * KCH + KCH + CCH;
        prep_kernel<<<(ptot + 255) / 256, 256, 0, stream>>>(
            W2, gfw, bn1g, bn1b, bn1m, bn1v, w1, W2bf, gws, shf, w1s);
        rfa_mfma2_kernel<true><<<grid, blk, 0, stream>>>(
            xx, w1, gfw, bn1g, bn1b, bn1m, bn1v, W2, W2bf, gws, shf, w1s,
            cb, bn2g, bn2b, bn2m, bn2v, o);
    } else {
        rfa_mfma2_kernel<false><<<grid, blk, 0, stream>>>(
            xx, w1, gfw, bn1g, bn1b, bn1m, bn1v, W2, nullptr, nullptr, nullptr, nullptr,
            cb, bn2g, bn2b, bn2m, bn2v, o);
    }
}

// Round 5
// 210.391 us; speedup vs baseline: 4.9537x; 1.1672x over previous
//
#include <hip/hip_runtime.h>
#include <hip/hip_bf16.h>

// RFAConv fused MFMA, round 5: software-pipelined neighborhood loads (next pass's
// 9 taps issued before current compute; chunk-crossing loads fly under barrier+GEMM)
// + packed v_pk_fma_f32 phase-1 math + hoisted boundary handling.

#define CCH  128
#define OCN  256
#define HH   96
#define WWD  96
#define KCH  1152
#define PIMG 9216
#define BNP  64       // pixels per block
#define NBLK 144
#define CC   32       // channels per chunk
#define KC   288
#define VP   296      // LDS row pitch (shorts), 16B-aligned rows
#define NT   512

using short8  = __attribute__((ext_vector_type(8))) short;
using f32x4   = __attribute__((ext_vector_type(4))) float;
using f32x2   = __attribute__((ext_vector_type(2))) float;

__device__ __forceinline__ ushort bf16bits(float f) {
    __hip_bfloat16 h = __float2bfloat16(f);
    return *reinterpret_cast<ushort*>(&h);
}

struct NB { f32x2 p[4]; float s; };   // 9 raw taps as 4 pairs + 1

// ---- prepass: W2->bf16, fold bn1 into dwconv weights (stride 12), w1/9 (stride 12) ----
__global__ void prep_kernel(const float* __restrict__ W2, const float* __restrict__ gfw,
                            const float* __restrict__ bn1g, const float* __restrict__ bn1b,
                            const float* __restrict__ bn1m, const float* __restrict__ bn1v,
                            const float* __restrict__ w1,
                            ushort* __restrict__ W2bf, float* __restrict__ gws,
                            float* __restrict__ shiftv, float* __restrict__ w1s) {
    int i = blockIdx.x * 256 + threadIdx.x;
    if (i < OCN * KCH) {
        W2bf[i] = bf16bits(W2[i]);
    } else if (i < OCN * KCH + KCH) {
        const int ch = i - OCN * KCH;
        const float sc = bn1g[ch] * rsqrtf(bn1v[ch] + 1e-5f);
        shiftv[ch] = bn1b[ch] - bn1m[ch] * sc;
        #pragma unroll
        for (int t = 0; t < 9; ++t) gws[ch * 12 + t] = gfw[ch * 9 + t] * sc;
    } else if (i < OCN * KCH + KCH + CCH) {
        const int c = i - OCN * KCH - KCH;
        #pragma unroll
        for (int n = 0; n < 9; ++n) w1s[c * 12 + n] = w1[c * 9 + n] * (1.f / 9.f);
    }
}

__device__ __forceinline__ NB load_nb(const float* __restrict__ xc,
                                      const int hro0, const int hro1, const int hro2,
                                      const int wx0, const int wx1, const int wx2) {
    NB r;
    float v0 = xc[hro0 + wx0], v1 = xc[hro0 + wx1], v2 = xc[hro0 + wx2];
    float v3 = xc[hro1 + wx0], v4 = xc[hro1 + wx1], v5 = xc[hro1 + wx2];
    float v6 = xc[hro2 + wx0], v7 = xc[hro2 + wx1], v8 = xc[hro2 + wx2];
    r.p[0] = f32x2{v0, v1}; r.p[1] = f32x2{v2, v3};
    r.p[2] = f32x2{v4, v5}; r.p[3] = f32x2{v6, v7};
    r.s = v8;
    return r;
}

template<bool FAST>
__global__ __launch_bounds__(NT, 4) void rfa_mfma3_kernel(
    const float* __restrict__ x,
    const float* __restrict__ w1,   const float* __restrict__ gfw,
    const float* __restrict__ bn1g, const float* __restrict__ bn1b,
    const float* __restrict__ bn1m, const float* __restrict__ bn1v,
    const float* __restrict__ W2f,
    const ushort* __restrict__ W2bf, const float* __restrict__ gws,
    const float* __restrict__ shiftv, const float* __restrict__ w1s,
    const float* __restrict__ cbias,
    const float* __restrict__ bn2g, const float* __restrict__ bn2b,
    const float* __restrict__ bn2m, const float* __restrict__ bn2v,
    float* __restrict__ out)
{
    __shared__ ushort vlds[2][BNP * VP];   // 75776 B

    const int tid = threadIdx.x;
    const int b   = blockIdx.x / NBLK;
    const int P0  = (blockIdx.x % NBLK) * BNP;

    const int px  = tid & 63;
    const int p   = P0 + px;
    const int h   = p / WWD;
    const int w   = p - h * WWD;
    const int wid = __builtin_amdgcn_readfirstlane(tid >> 6);   // 0..7 uniform
    const int l15 = px & 15;
    const int lhi = px >> 4;

    // ---- boundary precompute (once per thread) ----
    int hro[3], wxc[3];
    f32x2 okp[4];
    float ok8;
    {
        float okr[3], okc[3];
        #pragma unroll
        for (int d = 0; d < 3; ++d) {
            int hy = h + d - 1;
            okr[d] = ((unsigned)hy < (unsigned)HH) ? 1.f : 0.f;
            hro[d] = ((hy < 0) ? 0 : (hy > 95 ? 95 : hy)) * WWD;
            int wx = w + d - 1;
            okc[d] = ((unsigned)wx < (unsigned)WWD) ? 1.f : 0.f;
            wxc[d] = (wx < 0) ? 0 : (wx > 95 ? 95 : wx);
        }
        float o[9];
        #pragma unroll
        for (int dy = 0; dy < 3; ++dy)
            #pragma unroll
            for (int dx = 0; dx < 3; ++dx) o[dy*3+dx] = okr[dy] * okc[dx];
        okp[0] = f32x2{o[0], o[1]}; okp[1] = f32x2{o[2], o[3]};
        okp[2] = f32x2{o[4], o[5]}; okp[3] = f32x2{o[6], o[7]};
        ok8 = o[8];
    }

    f32x4 acc[2][4] = {};
    const float* xb = x + (size_t)b * CCH * PIMG;
    const int abase = (wid * 32 + l15) * KCH + lhi * 8;

    // channel for linear pass q (0..15): c = (q>>2)*32 + wid*4 + (q&3)
    auto chan = [&](int q) { return (q >> 2) * CC + wid * 4 + (q & 3); };

    NB nb = load_nb(xb + (size_t)chan(0) * PIMG, hro[0], hro[1], hro[2], wxc[0], wxc[1], wxc[2]);

    for (int ck = 0; ck < 4; ++ck) {
        ushort* vbuf = vlds[ck & 1];

        #pragma unroll
        for (int pass = 0; pass < 4; ++pass) {
            const int q  = ck * 4 + pass;
            const int qn = (q + 1 > 15) ? 15 : q + 1;
            // issue next pass's loads first (chunk-crossing ones fly under barrier+GEMM)
            NB nbn = load_nb(xb + (size_t)chan(qn) * PIMG,
                             hro[0], hro[1], hro[2], wxc[0], wxc[1], wxc[2]);

            // ---- compute current pass ----
            const int c  = chan(q);
            const int cl = wid * 4 + pass;
            f32x2 e[4];
            #pragma unroll
            for (int i = 0; i < 4; ++i) e[i] = nb.p[i] * okp[i];
            const float e8 = nb.s * ok8;
            f32x2 ps2 = (e[0] + e[1]) + (e[2] + e[3]);
            const float psum = ps2[0] + ps2[1] + e8;

            float at[9], ss = 0.f;
            if constexpr (FAST) {
                const float* w1r = w1s + c * 12;
                #pragma unroll
                for (int n = 0; n < 9; ++n) { at[n] = __expf(psum * w1r[n]); ss += at[n]; }
            } else {
                const float pooled = psum * (1.f / 9.f);
                const float* w1r = w1 + c * 9;
                #pragma unroll
                for (int n = 0; n < 9; ++n) { at[n] = __expf(pooled * w1r[n]); ss += at[n]; }
            }
            const float rs = __builtin_amdgcn_rcpf(ss);

            ushort* vp = vbuf + px * VP + cl * 9;
            #pragma unroll
            for (int n = 0; n < 9; ++n) {
                const int ch = c * 9 + n;
                float f;
                if constexpr (FAST) {
                    const f32x2* gp = reinterpret_cast<const f32x2*>(gws + ch * 12);
                    f32x2 f2 = f32x2{shiftv[ch], 0.f};
                    #pragma unroll
                    for (int t = 0; t < 4; ++t) f2 = __builtin_elementwise_fma(e[t], gp[t], f2);
                    f = f2[0] + f2[1];
                    f = fmaf(e8, gws[ch * 12 + 8], f);
                } else {
                    const float* gr = gfw + ch * 9;
                    float cv = 0.f;
                    cv = fmaf(e[0][0], gr[0], cv); cv = fmaf(e[0][1], gr[1], cv);
                    cv = fmaf(e[1][0], gr[2], cv); cv = fmaf(e[1][1], gr[3], cv);
                    cv = fmaf(e[2][0], gr[4], cv); cv = fmaf(e[2][1], gr[5], cv);
                    cv = fmaf(e[3][0], gr[6], cv); cv = fmaf(e[3][1], gr[7], cv);
                    cv = fmaf(e8, gr[8], cv);
                    const float sc = bn1g[ch] * rsqrtf(bn1v[ch] + 1e-5f);
                    f = (cv - bn1m[ch]) * sc + bn1b[ch];
                }
                f = fmaxf(f, 0.f) * (at[n] * rs);
                vp[n] = bf16bits(f);
            }
            nb = nbn;
        }
        __syncthreads();   // vbuf(ck) ready; other buffer free (see ordering proof in notes)

        // ---------- GEMM chunk ck: 9 ksteps of 32 ----------
        const int k0 = ck * KC;
        #pragma unroll 3
        for (int kk = 0; kk < 9; ++kk) {
            short8 afr[2], bfr[4];
            #pragma unroll
            for (int mi = 0; mi < 2; ++mi) {
                const int ai = abase + mi * 16 * KCH + k0 + kk * 32;
                if constexpr (FAST) {
                    afr[mi] = *reinterpret_cast<const short8*>(W2bf + ai);
                } else {
                    const f32x4 f0 = *reinterpret_cast<const f32x4*>(W2f + ai);
                    const f32x4 f1 = *reinterpret_cast<const f32x4*>(W2f + ai + 4);
                    short8 a;
                    a[0] = (short)bf16bits(f0[0]); a[1] = (short)bf16bits(f0[1]);
                    a[2] = (short)bf16bits(f0[2]); a[3] = (short)bf16bits(f0[3]);
                    a[4] = (short)bf16bits(f1[0]); a[5] = (short)bf16bits(f1[1]);
                    a[6] = (short)bf16bits(f1[2]); a[7] = (short)bf16bits(f1[3]);
                    afr[mi] = a;
                }
            }
            #pragma unroll
            for (int ni = 0; ni < 4; ++ni) {
                const ushort* bp = vbuf + (ni * 16 + l15) * VP + kk * 32 + lhi * 8;
                bfr[ni] = *reinterpret_cast<const short8*>(bp);
            }
            #pragma unroll
            for (int mi = 0; mi < 2; ++mi)
                #pragma unroll
                for (int ni = 0; ni < 4; ++ni)
                    acc[mi][ni] = __builtin_amdgcn_mfma_f32_16x16x32_bf16(
                        afr[mi], bfr[ni], acc[mi][ni], 0, 0, 0);
        }
    }

    // ---------- epilogue: bn2 + relu ----------
    #pragma unroll
    for (int mi = 0; mi < 2; ++mi) {
        #pragma unroll
        for (int r = 0; r < 4; ++r) {
            const int oc = wid * 32 + mi * 16 + lhi * 4 + r;
            const float s2 = bn2g[oc] * rsqrtf(bn2v[oc] + 1e-5f);
            const float t2 = (cbias[oc] - bn2m[oc]) * s2 + bn2b[oc];
            float* op = out + ((size_t)(b * OCN + oc)) * PIMG + P0;
            #pragma unroll
            for (int ni = 0; ni < 4; ++ni)
                op[ni * 16 + l15] = fmaxf(fmaf(acc[mi][ni][r], s2, t2), 0.f);
        }
    }
}

extern "C" void kernel_launch(void* const* d_in, const int* in_sizes, int n_in,
                              void* d_out, int out_size, void* d_ws, size_t ws_size,
                              hipStream_t stream) {
    const float* xx   = (const float*)d_in[0];
    const float* w1   = (const float*)d_in[1];
    const float* gfw  = (const float*)d_in[2];
    const float* bn1g = (const float*)d_in[3];
    const float* bn1b = (const float*)d_in[4];
    const float* bn1m = (const float*)d_in[5];
    const float* bn1v = (const float*)d_in[6];
    const float* W2   = (const float*)d_in[7];
    const float* cb   = (const float*)d_in[8];
    const float* bn2g = (const float*)d_in[9];
    const float* bn2b = (const float*)d_in[10];
    const float* bn2m = (const float*)d_in[11];
    const float* bn2v = (const float*)d_in[12];
    float* o = (float*)d_out;

    const size_t off_gws   = (size_t)OCN * KCH * sizeof(ushort);
    const size_t off_shift = off_gws + (size_t)KCH * 12 * sizeof(float);
    const size_t off_w1s   = off_shift + (size_t)KCH * sizeof(float);
    const size_t ws_need   = off_w1s + (size_t)CCH * 12 * sizeof(float);

    dim3 grid(8 * NBLK);
    dim3 blk(NT);

    if (ws_size >= ws_need) {
        ushort* W2bf = (ushort*)d_ws;
        float*  gwsp = (float*)((char*)d_ws + off_gws);
        float*  shf  = (float*)((char*)d_ws + off_shift);
        float*  w1sp = (float*)((char*)d_ws + off_w1s);
        const int ptot = OCN * KCH + KCH + CCH;
        prep_kernel<<<(ptot + 255) / 256, 256, 0, stream>>>(
            W2, gfw, bn1g, bn1b, bn1m, bn1v, w1, W2bf, gwsp, shf, w1sp);
        rfa_mfma3_kernel<true><<<grid, blk, 0, stream>>>(
            xx, w1, gfw, bn1g, bn1b, bn1m, bn1v, W2, W2bf, gwsp, shf, w1sp,
            cb, bn2g, bn2b, bn2m, bn2v, o);
    } else {
        rfa_mfma3_kernel<false><<<grid, blk, 0, stream>>>(
            xx, w1, gfw, bn1g, bn1b, bn1m, bn1v, W2, nullptr, nullptr, nullptr, nullptr,
            cb, bn2g, bn2b, bn2m, bn2v, o);
    }
}